// Round 7
// baseline (826.070 us; speedup 1.0000x reference)
//
#include <hip/hip_runtime.h>
#include <hip/hip_fp16.h>
#include <math.h>

// GAT 2-layer. R7: fp16 gather tables (xw/hw stored as __half, fp32 accumulate)
// to halve the random-gather traffic in both agg kernels; wave-cooperative
// bucket flush in kP1 (was single-thread serial scatter).

#define CAPS 32
#define STRIDE 33
#define NBMAX 128

__device__ __forceinline__ float lrelu(float v) { return v >= 0.f ? v : 0.2f * v; }
__device__ __forceinline__ float eluf(float v)  { return v > 0.f ? v : expm1f(v); }

// ---------------- transform body: 8 waves/block, 8 nodes/wave, lane = col ----
template<int K, int HEADS>
__device__ __forceinline__ void tf_body8(
    int tfb, const float* __restrict__ xin, const float* __restrict__ W,
    const float* __restrict__ attS, const float* __restrict__ attD,
    int N, __half* __restrict__ xw, float* __restrict__ as, float* __restrict__ ad,
    float* Wl)
{
    const float4* Wv = (const float4*)W;
    float4* Wlv = (float4*)Wl;
    for (int i = threadIdx.x; i < K * 16; i += 512) Wlv[i] = Wv[i];
    __syncthreads();
    int wave = threadIdx.x >> 6;
    int lane = threadIdx.x & 63;
    int n0 = tfb * 64 + wave * 8;
    if (n0 >= N) return;
    int cnt = min(8, N - n0);
    const float4* xp[8];
    #pragma unroll
    for (int j = 0; j < 8; j++)
        xp[j] = (const float4*)(xin + (size_t)(n0 + (j < cnt ? j : 0)) * K);
    float acc[8] = {0.f,0.f,0.f,0.f,0.f,0.f,0.f,0.f};
    #pragma unroll 2
    for (int k4 = 0; k4 < K / 4; k4++) {
        float4 xv[8];
        #pragma unroll
        for (int j = 0; j < 8; j++) xv[j] = xp[j][k4];
        int kb = k4 * 256 + lane;
        float w0 = Wl[kb], w1 = Wl[kb + 64], w2 = Wl[kb + 128], w3 = Wl[kb + 192];
        #pragma unroll
        for (int j = 0; j < 8; j++) {
            acc[j] = fmaf(xv[j].x, w0, acc[j]);
            acc[j] = fmaf(xv[j].y, w1, acc[j]);
            acc[j] = fmaf(xv[j].z, w2, acc[j]);
            acc[j] = fmaf(xv[j].w, w3, acc[j]);
        }
    }
    float aSl = attS[lane], aDl = attD[lane];
    #pragma unroll
    for (int j = 0; j < 8; j++) {
        if (j < cnt) {
            int n = n0 + j;
            xw[(size_t)n * 64 + lane] = __float2half(acc[j]);
            float ps = acc[j] * aSl, pd = acc[j] * aDl;
            if (HEADS == 8) {
                ps += __shfl_xor(ps, 1, 64); pd += __shfl_xor(pd, 1, 64);
                ps += __shfl_xor(ps, 2, 64); pd += __shfl_xor(pd, 2, 64);
                ps += __shfl_xor(ps, 4, 64); pd += __shfl_xor(pd, 4, 64);
                if ((lane & 7) == 0) {
                    as[(size_t)n * 8 + (lane >> 3)] = ps;
                    ad[(size_t)n * 8 + (lane >> 3)] = pd;
                }
            } else {
                #pragma unroll
                for (int off = 1; off < 64; off <<= 1) {
                    ps += __shfl_xor(ps, off, 64);
                    pd += __shfl_xor(pd, off, 64);
                }
                if (lane == 0) { as[n] = ps; ad[n] = pd; }
            }
        }
    }
}

// ---------------- fused: phase1 binning || tf0 ----------------
__global__ __launch_bounds__(512, 4) void kP1(
    const float* __restrict__ x, const float* __restrict__ W0,
    const float* __restrict__ aS, const float* __restrict__ aD,
    int N, __half* __restrict__ xw, float* __restrict__ as, float* __restrict__ ad,
    int tfBlocks,
    const int* __restrict__ src, const int* __restrict__ dst, int E,
    int p1Blocks, int perBlock,
    unsigned* __restrict__ bucketBuf, int* __restrict__ gcur, int NB, int cap)
{
    __shared__ __align__(16) char smem[128 * 64 * 4];
    int b = blockIdx.x;
    int T = tfBlocks + p1Blocks;
    int lo = (int)((long long)b * tfBlocks / T);
    int hi = (int)((long long)(b + 1) * tfBlocks / T);
    if (hi > lo) {
        tf_body8<128, 8>(lo, x, W0, aS, aD, N, xw, as, ad, (float*)smem);
    } else {
        int pb = b - hi;
        unsigned* stage = (unsigned*)smem;
        int* scnt = (int*)(smem + NBMAX * STRIDE * 4);
        int tid = threadIdx.x;
        int wave = tid >> 6, lane = tid & 63;
        for (int i = tid; i < NB; i += 512) scnt[i] = 0;
        __syncthreads();
        int e0 = pb * perBlock, e1 = min(E, e0 + perBlock);
        for (int base = e0; base < e1; base += 512) {
            int i = base + tid;
            if (i < e1) {
                int d = dst[i], s = src[i];
                int bk = d >> 10;
                unsigned rec = ((unsigned)(d & 1023) << 22) | (unsigned)s;
                int pos = atomicAdd(&scnt[bk], 1);
                if (pos < CAPS) {
                    stage[bk * STRIDE + pos] = rec;
                } else {
                    int g = atomicAdd(&gcur[bk], 1);
                    bucketBuf[(size_t)bk * cap + g] = rec;
                }
            }
            __syncthreads();
            // wave-cooperative flush: wave w handles buckets w, w+8, ...
            for (int bk = wave; bk < NB; bk += 8) {
                int n = min(scnt[bk], CAPS);
                int g16 = n & ~15;
                if (g16) {
                    int gb = 0;
                    if (lane == 0) gb = atomicAdd(&gcur[bk], g16);
                    gb = __shfl(gb, 0, 64);
                    if (lane < g16)
                        bucketBuf[(size_t)bk * cap + gb + lane] = stage[bk * STRIDE + lane];
                    int left = n - g16;
                    unsigned tmp = 0;
                    if (lane < left) tmp = stage[bk * STRIDE + g16 + lane];  // g16>=16>left, no overlap
                    if (lane < left) stage[bk * STRIDE + lane] = tmp;
                    if (lane == 0) scnt[bk] = left;
                }
            }
            __syncthreads();
        }
        for (int bk = wave; bk < NB; bk += 8) {
            int n = min(scnt[bk], CAPS);
            if (n > 0) {
                int gb = 0;
                if (lane == 0) gb = atomicAdd(&gcur[bk], n);
                gb = __shfl(gb, 0, 64);
                if (lane < n)
                    bucketBuf[(size_t)bk * cap + gb + lane] = stage[bk * STRIDE + lane];
            }
        }
    }
}

// ---------------- phase2: per-bucket CSR build ----------------
__global__ __launch_bounds__(256) void kP2(
    const unsigned* __restrict__ bucketBuf, const int* __restrict__ gcur,
    int NB, int cap, int N, int* __restrict__ row, int* __restrict__ adj)
{
    __shared__ int deg[1024];
    __shared__ int curl[1024];
    __shared__ int sc[256];
    int b = blockIdx.x, tid = threadIdx.x;
    int lo = b << 10;
    int hi = min(N, lo + 1024);
    int cnt = hi - lo;
    int size = min(gcur[b], cap);
    sc[tid] = (tid < b) ? gcur[tid] : 0;
    __syncthreads();
    for (int off = 128; off > 0; off >>= 1) {
        if (tid < off) sc[tid] += sc[tid + off];
        __syncthreads();
    }
    int bbase = sc[0];
    __syncthreads();
    for (int i = tid; i < 1024; i += 256) deg[i] = 0;
    __syncthreads();
    const unsigned* buf = bucketBuf + (size_t)b * cap;
    for (int e = tid; e < size; e += 256) atomicAdd(&deg[buf[e] >> 22], 1);
    __syncthreads();
    int dv[4]; int s = 0;
    #pragma unroll
    for (int j = 0; j < 4; j++) { dv[j] = deg[tid * 4 + j]; s += dv[j]; }
    sc[tid] = s; __syncthreads();
    for (int off = 1; off < 256; off <<= 1) {
        int xv = (tid >= off) ? sc[tid - off] : 0;
        __syncthreads();
        sc[tid] += xv;
        __syncthreads();
    }
    int o = (tid ? sc[tid - 1] : 0);
    #pragma unroll
    for (int j = 0; j < 4; j++) {
        int loc = tid * 4 + j;
        curl[loc] = o;
        if (loc < cnt) row[lo + loc] = bbase + o;
        o += dv[j];
    }
    if (b == NB - 1 && tid == 0) row[N] = bbase + size;
    __syncthreads();
    for (int e = tid; e < size; e += 256) {
        unsigned r = buf[e];
        int l = r >> 22;
        int p = atomicAdd(&curl[l], 1);
        adj[bbase + p] = (int)(r & 0x3FFFFF);
    }
}

// ---------------- layer0 aggregation + fused layer1 transform ----------------
__global__ __launch_bounds__(256) void k_agg8_tf1(
    const __half* __restrict__ xw, const float* __restrict__ as, const float* __restrict__ ad,
    const int* __restrict__ row, const int* __restrict__ adj,
    const float* __restrict__ bias, const float* __restrict__ W1,
    const float* __restrict__ aS1, const float* __restrict__ aD1,
    int N, __half* __restrict__ hw, float* __restrict__ as1, float* __restrict__ ad1)
{
    __shared__ float Wl[64 * 64];
    {
        const float4* Wv = (const float4*)W1;
        float4* Wlv = (float4*)Wl;
        for (int i = threadIdx.x; i < 1024; i += 256) Wlv[i] = Wv[i];
    }
    __syncthreads();
    int n = (blockIdx.x * 256 + threadIdx.x) >> 6;
    int lane = threadIdx.x & 63;
    if (n >= N) return;
    int rs = row[n], re = row[n + 1];
    int hh = lane & 7;
    int e8 = lane >> 3;
    int hb = lane >> 3;
    float adv = ad[(size_t)n * 8 + hh];
    float shift = lrelu(as[(size_t)n * 8 + hh] + adv);
    float acc = __half2float(xw[(size_t)n * 64 + lane]);   // self edge, w = 1
    float acc2 = 0.f;
    float dsum = 0.f;
    int j = rs;
    for (; j + 8 <= re; j += 8) {
        int s = adj[j + e8];
        float e = lrelu(as[(size_t)s * 8 + hh] + adv);
        float w = __expf(e - shift);
        dsum += w;
        #pragma unroll
        for (int t = 0; t < 8; t += 2) {
            float we0 = __shfl(w, t * 8 + hb, 64);
            int   se0 = __shfl(s, t * 8, 64);
            float we1 = __shfl(w, t * 8 + 8 + hb, 64);
            int   se1 = __shfl(s, t * 8 + 8, 64);
            acc  = fmaf(we0, __half2float(xw[(size_t)se0 * 64 + lane]), acc);
            acc2 = fmaf(we1, __half2float(xw[(size_t)se1 * 64 + lane]), acc2);
        }
    }
    int rem = re - j;
    if (rem > 0) {
        int jj = j + e8;
        bool v = jj < re;
        int s = adj[v ? jj : rs];
        float e = lrelu(as[(size_t)s * 8 + hh] + adv);
        float w = v ? __expf(e - shift) : 0.f;
        dsum += w;
        for (int t = 0; t < rem; t++) {
            float we = __shfl(w, t * 8 + hb, 64);
            int   se = __shfl(s, t * 8, 64);
            acc = fmaf(we, __half2float(xw[(size_t)se * 64 + lane]), acc);
        }
    }
    acc += acc2;
    dsum += __shfl_xor(dsum, 8, 64);
    dsum += __shfl_xor(dsum, 16, 64);
    dsum += __shfl_xor(dsum, 32, 64);
    float denom = 1.f + __shfl(dsum, hb, 64);
    float h = eluf(acc / denom + bias[lane]);
    // ---- fused tf1 ----
    float a1 = 0.f;
    #pragma unroll 16
    for (int k = 0; k < 64; k++) {
        float hk = __shfl(h, k, 64);
        a1 = fmaf(hk, Wl[k * 64 + lane], a1);
    }
    hw[(size_t)n * 64 + lane] = __float2half(a1);
    float ps = a1 * aS1[lane], pd = a1 * aD1[lane];
    #pragma unroll
    for (int off = 1; off < 64; off <<= 1) {
        ps += __shfl_xor(ps, off, 64);
        pd += __shfl_xor(pd, off, 64);
    }
    if (lane == 0) { as1[n] = ps; ad1[n] = pd; }
}

// ---------------- layer1 aggregation ----------------
__global__ __launch_bounds__(256) void k_agg1(
    const __half* __restrict__ hw, const float* __restrict__ as, const float* __restrict__ ad,
    const int* __restrict__ row, const int* __restrict__ adj,
    const float* __restrict__ bias, int N, float* __restrict__ outp)
{
    int n = (blockIdx.x * 256 + threadIdx.x) >> 6;
    int lane = threadIdx.x & 63;
    if (n >= N) return;
    int rs = row[n], re = row[n + 1];
    int e8 = lane >> 3;
    float adv = ad[n];
    float shift = lrelu(as[n] + adv);
    float acc = __half2float(hw[(size_t)n * 64 + lane]);
    float acc2 = 0.f;
    float dsum = 0.f;
    int j = rs;
    for (; j + 8 <= re; j += 8) {
        int s = adj[j + e8];
        float e = lrelu(as[s] + adv);
        float w = __expf(e - shift);
        dsum += w;
        #pragma unroll
        for (int t = 0; t < 8; t += 2) {
            float we0 = __shfl(w, t * 8, 64);
            int   se0 = __shfl(s, t * 8, 64);
            float we1 = __shfl(w, t * 8 + 8, 64);
            int   se1 = __shfl(s, t * 8 + 8, 64);
            acc  = fmaf(we0, __half2float(hw[(size_t)se0 * 64 + lane]), acc);
            acc2 = fmaf(we1, __half2float(hw[(size_t)se1 * 64 + lane]), acc2);
        }
    }
    int rem = re - j;
    if (rem > 0) {
        int jj = j + e8;
        bool v = jj < re;
        int s = adj[v ? jj : rs];
        float e = lrelu(as[s] + adv);
        float w = v ? __expf(e - shift) : 0.f;
        dsum += w;
        for (int t = 0; t < rem; t++) {
            float we = __shfl(w, t * 8, 64);
            int   se = __shfl(s, t * 8, 64);
            acc = fmaf(we, __half2float(hw[(size_t)se * 64 + lane]), acc);
        }
    }
    acc += acc2;
    dsum += __shfl_xor(dsum, 8, 64);
    dsum += __shfl_xor(dsum, 16, 64);
    dsum += __shfl_xor(dsum, 32, 64);
    float denom = 1.f + dsum;
    float o = acc / denom + bias[lane];
    outp[(size_t)n * 64 + lane] = eluf(o);
}

extern "C" void kernel_launch(void* const* d_in, const int* in_sizes, int n_in,
                              void* d_out, int out_size, void* d_ws, size_t ws_size,
                              hipStream_t stream)
{
    const float* x   = (const float*)d_in[0];
    const int*   ei  = (const int*)d_in[1];
    const float* W0  = (const float*)d_in[2];
    const float* aS0 = (const float*)d_in[3];
    const float* aD0 = (const float*)d_in[4];
    const float* b0  = (const float*)d_in[5];
    const float* W1  = (const float*)d_in[6];
    const float* aS1 = (const float*)d_in[7];
    const float* aD1 = (const float*)d_in[8];
    const float* b1  = (const float*)d_in[9];

    const int N = in_sizes[0] / 128;
    const int E = in_sizes[1] / 2;
    const int* srcp = ei;
    const int* dstp = ei + E;

    const int NB  = (N + 1023) >> 10;
    const int cap = E / NB + 4096;

    char* ws = (char*)d_ws;
    size_t off = 0;
    auto alloc = [&](size_t bytes) -> size_t {
        size_t o = off;
        off = (o + bytes + 255) & ~(size_t)255;
        return o;
    };
    __half* B1 = (__half*)(ws + alloc((size_t)N * 64 * 2));     // xw (half)
    // B2 (hw half) overlays bucketBuf (dead after kP2)
    size_t b2Bytes = (size_t)N * 64 * 2;
    size_t bkBytes = (size_t)NB * cap * 4;
    char*  region  = ws + alloc(b2Bytes > bkBytes ? b2Bytes : bkBytes);
    __half*   B2        = (__half*)region;
    unsigned* bucketBuf = (unsigned*)region;
    float* as0 = (float*)(ws + alloc((size_t)N * 8 * 4));
    float* ad0 = (float*)(ws + alloc((size_t)N * 8 * 4));
    float* as1 = (float*)(ws + alloc((size_t)N * 4));
    float* ad1 = (float*)(ws + alloc((size_t)N * 4));
    int*   row = (int*)(ws + alloc((size_t)(N + 1) * 4));
    int*   adj = (int*)(ws + alloc((size_t)E * 4));
    int*  gcur = (int*)(ws + alloc((size_t)NB * 4));

    const int tfBlocks = (N + 63) / 64;
    const int p1Blocks = 1024;
    const int perBlock = (E + p1Blocks - 1) / p1Blocks;

    hipMemsetAsync(gcur, 0, (size_t)NB * 4, stream);
    kP1<<<tfBlocks + p1Blocks, 512, 0, stream>>>(
        x, W0, aS0, aD0, N, B1, as0, ad0, tfBlocks,
        srcp, dstp, E, p1Blocks, perBlock, bucketBuf, gcur, NB, cap);
    kP2<<<NB, 256, 0, stream>>>(bucketBuf, gcur, NB, cap, N, row, adj);

    const int agBlocks = (N + 3) / 4;
    k_agg8_tf1<<<agBlocks, 256, 0, stream>>>(B1, as0, ad0, row, adj, b0,
                                             W1, aS1, aD1, N, B2, as1, ad1);
    k_agg1<<<agBlocks, 256, 0, stream>>>(B2, as1, ad1, row, adj, b1, N, (float*)d_out);
}

// Round 8
// 497.912 us; speedup vs baseline: 1.6591x; 1.6591x over previous
//
#include <hip/hip_runtime.h>
#include <hip/hip_fp16.h>
#include <math.h>

// GAT 2-layer. R8: fp16 gather tables (xw/hw as __half, fp32 accumulate) +
// kP1 flush reverted to R6 per-thread parallel version (R7's wave-coop flush
// serialized dependent global atomics -> 3x regression).

#define CAPS 32
#define STRIDE 33
#define NBMAX 128

__device__ __forceinline__ float lrelu(float v) { return v >= 0.f ? v : 0.2f * v; }
__device__ __forceinline__ float eluf(float v)  { return v > 0.f ? v : expm1f(v); }

// ---------------- transform body: 8 waves/block, 8 nodes/wave, lane = col ----
template<int K, int HEADS>
__device__ __forceinline__ void tf_body8(
    int tfb, const float* __restrict__ xin, const float* __restrict__ W,
    const float* __restrict__ attS, const float* __restrict__ attD,
    int N, __half* __restrict__ xw, float* __restrict__ as, float* __restrict__ ad,
    float* Wl)
{
    const float4* Wv = (const float4*)W;
    float4* Wlv = (float4*)Wl;
    for (int i = threadIdx.x; i < K * 16; i += 512) Wlv[i] = Wv[i];
    __syncthreads();
    int wave = threadIdx.x >> 6;
    int lane = threadIdx.x & 63;
    int n0 = tfb * 64 + wave * 8;
    if (n0 >= N) return;
    int cnt = min(8, N - n0);
    const float4* xp[8];
    #pragma unroll
    for (int j = 0; j < 8; j++)
        xp[j] = (const float4*)(xin + (size_t)(n0 + (j < cnt ? j : 0)) * K);
    float acc[8] = {0.f,0.f,0.f,0.f,0.f,0.f,0.f,0.f};
    #pragma unroll 2
    for (int k4 = 0; k4 < K / 4; k4++) {
        float4 xv[8];
        #pragma unroll
        for (int j = 0; j < 8; j++) xv[j] = xp[j][k4];
        int kb = k4 * 256 + lane;
        float w0 = Wl[kb], w1 = Wl[kb + 64], w2 = Wl[kb + 128], w3 = Wl[kb + 192];
        #pragma unroll
        for (int j = 0; j < 8; j++) {
            acc[j] = fmaf(xv[j].x, w0, acc[j]);
            acc[j] = fmaf(xv[j].y, w1, acc[j]);
            acc[j] = fmaf(xv[j].z, w2, acc[j]);
            acc[j] = fmaf(xv[j].w, w3, acc[j]);
        }
    }
    float aSl = attS[lane], aDl = attD[lane];
    #pragma unroll
    for (int j = 0; j < 8; j++) {
        if (j < cnt) {
            int n = n0 + j;
            xw[(size_t)n * 64 + lane] = __float2half(acc[j]);
            float ps = acc[j] * aSl, pd = acc[j] * aDl;
            if (HEADS == 8) {
                ps += __shfl_xor(ps, 1, 64); pd += __shfl_xor(pd, 1, 64);
                ps += __shfl_xor(ps, 2, 64); pd += __shfl_xor(pd, 2, 64);
                ps += __shfl_xor(ps, 4, 64); pd += __shfl_xor(pd, 4, 64);
                if ((lane & 7) == 0) {
                    as[(size_t)n * 8 + (lane >> 3)] = ps;
                    ad[(size_t)n * 8 + (lane >> 3)] = pd;
                }
            } else {
                #pragma unroll
                for (int off = 1; off < 64; off <<= 1) {
                    ps += __shfl_xor(ps, off, 64);
                    pd += __shfl_xor(pd, off, 64);
                }
                if (lane == 0) { as[n] = ps; ad[n] = pd; }
            }
        }
    }
}

// ---------------- fused: phase1 binning || tf0 ----------------
__global__ __launch_bounds__(512, 4) void kP1(
    const float* __restrict__ x, const float* __restrict__ W0,
    const float* __restrict__ aS, const float* __restrict__ aD,
    int N, __half* __restrict__ xw, float* __restrict__ as, float* __restrict__ ad,
    int tfBlocks,
    const int* __restrict__ src, const int* __restrict__ dst, int E,
    int p1Blocks, int perBlock,
    unsigned* __restrict__ bucketBuf, int* __restrict__ gcur, int NB, int cap)
{
    __shared__ __align__(16) char smem[128 * 64 * 4];
    int b = blockIdx.x;
    int T = tfBlocks + p1Blocks;
    int lo = (int)((long long)b * tfBlocks / T);
    int hi = (int)((long long)(b + 1) * tfBlocks / T);
    if (hi > lo) {
        tf_body8<128, 8>(lo, x, W0, aS, aD, N, xw, as, ad, (float*)smem);
    } else {
        int pb = b - hi;
        unsigned* stage = (unsigned*)smem;
        int* scnt = (int*)(smem + NBMAX * STRIDE * 4);
        int tid = threadIdx.x;
        for (int i = tid; i < NB; i += 512) scnt[i] = 0;
        __syncthreads();
        int e0 = pb * perBlock, e1 = min(E, e0 + perBlock);
        for (int base = e0; base < e1; base += 512) {
            int i = base + tid;
            if (i < e1) {
                int d = dst[i], s = src[i];
                int bk = d >> 10;
                unsigned rec = ((unsigned)(d & 1023) << 22) | (unsigned)s;
                int pos = atomicAdd(&scnt[bk], 1);
                if (pos < CAPS) {
                    stage[bk * STRIDE + pos] = rec;
                } else {
                    int g = atomicAdd(&gcur[bk], 1);
                    bucketBuf[(size_t)bk * cap + g] = rec;
                }
            }
            __syncthreads();
            // per-thread parallel flush: thread tid owns bucket tid
            if (tid < NB) {
                int n = min(scnt[tid], CAPS);
                int g16 = n & ~15;
                if (g16) {
                    int gb = atomicAdd(&gcur[tid], g16);
                    unsigned* gp = &bucketBuf[(size_t)tid * cap + gb];
                    for (int j = 0; j < g16; j++) gp[j] = stage[tid * STRIDE + j];
                    for (int j = 0; j < n - g16; j++)
                        stage[tid * STRIDE + j] = stage[tid * STRIDE + g16 + j];
                    scnt[tid] = n - g16;
                } else {
                    scnt[tid] = n;
                }
            }
            __syncthreads();
        }
        if (tid < NB) {
            int n = scnt[tid];
            if (n > 0) {
                int gb = atomicAdd(&gcur[tid], n);
                unsigned* gp = &bucketBuf[(size_t)tid * cap + gb];
                for (int j = 0; j < n; j++) gp[j] = stage[tid * STRIDE + j];
            }
        }
    }
}

// ---------------- phase2: per-bucket CSR build ----------------
__global__ __launch_bounds__(256) void kP2(
    const unsigned* __restrict__ bucketBuf, const int* __restrict__ gcur,
    int NB, int cap, int N, int* __restrict__ row, int* __restrict__ adj)
{
    __shared__ int deg[1024];
    __shared__ int curl[1024];
    __shared__ int sc[256];
    int b = blockIdx.x, tid = threadIdx.x;
    int lo = b << 10;
    int hi = min(N, lo + 1024);
    int cnt = hi - lo;
    int size = min(gcur[b], cap);
    sc[tid] = (tid < b) ? gcur[tid] : 0;
    __syncthreads();
    for (int off = 128; off > 0; off >>= 1) {
        if (tid < off) sc[tid] += sc[tid + off];
        __syncthreads();
    }
    int bbase = sc[0];
    __syncthreads();
    for (int i = tid; i < 1024; i += 256) deg[i] = 0;
    __syncthreads();
    const unsigned* buf = bucketBuf + (size_t)b * cap;
    for (int e = tid; e < size; e += 256) atomicAdd(&deg[buf[e] >> 22], 1);
    __syncthreads();
    int dv[4]; int s = 0;
    #pragma unroll
    for (int j = 0; j < 4; j++) { dv[j] = deg[tid * 4 + j]; s += dv[j]; }
    sc[tid] = s; __syncthreads();
    for (int off = 1; off < 256; off <<= 1) {
        int xv = (tid >= off) ? sc[tid - off] : 0;
        __syncthreads();
        sc[tid] += xv;
        __syncthreads();
    }
    int o = (tid ? sc[tid - 1] : 0);
    #pragma unroll
    for (int j = 0; j < 4; j++) {
        int loc = tid * 4 + j;
        curl[loc] = o;
        if (loc < cnt) row[lo + loc] = bbase + o;
        o += dv[j];
    }
    if (b == NB - 1 && tid == 0) row[N] = bbase + size;
    __syncthreads();
    for (int e = tid; e < size; e += 256) {
        unsigned r = buf[e];
        int l = r >> 22;
        int p = atomicAdd(&curl[l], 1);
        adj[bbase + p] = (int)(r & 0x3FFFFF);
    }
}

// ---------------- layer0 aggregation + fused layer1 transform ----------------
__global__ __launch_bounds__(256) void k_agg8_tf1(
    const __half* __restrict__ xw, const float* __restrict__ as, const float* __restrict__ ad,
    const int* __restrict__ row, const int* __restrict__ adj,
    const float* __restrict__ bias, const float* __restrict__ W1,
    const float* __restrict__ aS1, const float* __restrict__ aD1,
    int N, __half* __restrict__ hw, float* __restrict__ as1, float* __restrict__ ad1)
{
    __shared__ float Wl[64 * 64];
    {
        const float4* Wv = (const float4*)W1;
        float4* Wlv = (float4*)Wl;
        for (int i = threadIdx.x; i < 1024; i += 256) Wlv[i] = Wv[i];
    }
    __syncthreads();
    int n = (blockIdx.x * 256 + threadIdx.x) >> 6;
    int lane = threadIdx.x & 63;
    if (n >= N) return;
    int rs = row[n], re = row[n + 1];
    int hh = lane & 7;
    int e8 = lane >> 3;
    int hb = lane >> 3;
    float adv = ad[(size_t)n * 8 + hh];
    float shift = lrelu(as[(size_t)n * 8 + hh] + adv);
    float acc = __half2float(xw[(size_t)n * 64 + lane]);   // self edge, w = 1
    float acc2 = 0.f;
    float dsum = 0.f;
    int j = rs;
    for (; j + 8 <= re; j += 8) {
        int s = adj[j + e8];
        float e = lrelu(as[(size_t)s * 8 + hh] + adv);
        float w = __expf(e - shift);
        dsum += w;
        #pragma unroll
        for (int t = 0; t < 8; t += 2) {
            float we0 = __shfl(w, t * 8 + hb, 64);
            int   se0 = __shfl(s, t * 8, 64);
            float we1 = __shfl(w, t * 8 + 8 + hb, 64);
            int   se1 = __shfl(s, t * 8 + 8, 64);
            acc  = fmaf(we0, __half2float(xw[(size_t)se0 * 64 + lane]), acc);
            acc2 = fmaf(we1, __half2float(xw[(size_t)se1 * 64 + lane]), acc2);
        }
    }
    int rem = re - j;
    if (rem > 0) {
        int jj = j + e8;
        bool v = jj < re;
        int s = adj[v ? jj : rs];
        float e = lrelu(as[(size_t)s * 8 + hh] + adv);
        float w = v ? __expf(e - shift) : 0.f;
        dsum += w;
        for (int t = 0; t < rem; t++) {
            float we = __shfl(w, t * 8 + hb, 64);
            int   se = __shfl(s, t * 8, 64);
            acc = fmaf(we, __half2float(xw[(size_t)se * 64 + lane]), acc);
        }
    }
    acc += acc2;
    dsum += __shfl_xor(dsum, 8, 64);
    dsum += __shfl_xor(dsum, 16, 64);
    dsum += __shfl_xor(dsum, 32, 64);
    float denom = 1.f + __shfl(dsum, hb, 64);
    float h = eluf(acc / denom + bias[lane]);
    // ---- fused tf1 ----
    float a1 = 0.f;
    #pragma unroll 16
    for (int k = 0; k < 64; k++) {
        float hk = __shfl(h, k, 64);
        a1 = fmaf(hk, Wl[k * 64 + lane], a1);
    }
    hw[(size_t)n * 64 + lane] = __float2half(a1);
    float ps = a1 * aS1[lane], pd = a1 * aD1[lane];
    #pragma unroll
    for (int off = 1; off < 64; off <<= 1) {
        ps += __shfl_xor(ps, off, 64);
        pd += __shfl_xor(pd, off, 64);
    }
    if (lane == 0) { as1[n] = ps; ad1[n] = pd; }
}

// ---------------- layer1 aggregation ----------------
__global__ __launch_bounds__(256) void k_agg1(
    const __half* __restrict__ hw, const float* __restrict__ as, const float* __restrict__ ad,
    const int* __restrict__ row, const int* __restrict__ adj,
    const float* __restrict__ bias, int N, float* __restrict__ outp)
{
    int n = (blockIdx.x * 256 + threadIdx.x) >> 6;
    int lane = threadIdx.x & 63;
    if (n >= N) return;
    int rs = row[n], re = row[n + 1];
    int e8 = lane >> 3;
    float adv = ad[n];
    float shift = lrelu(as[n] + adv);
    float acc = __half2float(hw[(size_t)n * 64 + lane]);
    float acc2 = 0.f;
    float dsum = 0.f;
    int j = rs;
    for (; j + 8 <= re; j += 8) {
        int s = adj[j + e8];
        float e = lrelu(as[s] + adv);
        float w = __expf(e - shift);
        dsum += w;
        #pragma unroll
        for (int t = 0; t < 8; t += 2) {
            float we0 = __shfl(w, t * 8, 64);
            int   se0 = __shfl(s, t * 8, 64);
            float we1 = __shfl(w, t * 8 + 8, 64);
            int   se1 = __shfl(s, t * 8 + 8, 64);
            acc  = fmaf(we0, __half2float(hw[(size_t)se0 * 64 + lane]), acc);
            acc2 = fmaf(we1, __half2float(hw[(size_t)se1 * 64 + lane]), acc2);
        }
    }
    int rem = re - j;
    if (rem > 0) {
        int jj = j + e8;
        bool v = jj < re;
        int s = adj[v ? jj : rs];
        float e = lrelu(as[s] + adv);
        float w = v ? __expf(e - shift) : 0.f;
        dsum += w;
        for (int t = 0; t < rem; t++) {
            float we = __shfl(w, t * 8, 64);
            int   se = __shfl(s, t * 8, 64);
            acc = fmaf(we, __half2float(hw[(size_t)se * 64 + lane]), acc);
        }
    }
    acc += acc2;
    dsum += __shfl_xor(dsum, 8, 64);
    dsum += __shfl_xor(dsum, 16, 64);
    dsum += __shfl_xor(dsum, 32, 64);
    float denom = 1.f + dsum;
    float o = acc / denom + bias[lane];
    outp[(size_t)n * 64 + lane] = eluf(o);
}

extern "C" void kernel_launch(void* const* d_in, const int* in_sizes, int n_in,
                              void* d_out, int out_size, void* d_ws, size_t ws_size,
                              hipStream_t stream)
{
    const float* x   = (const float*)d_in[0];
    const int*   ei  = (const int*)d_in[1];
    const float* W0  = (const float*)d_in[2];
    const float* aS0 = (const float*)d_in[3];
    const float* aD0 = (const float*)d_in[4];
    const float* b0  = (const float*)d_in[5];
    const float* W1  = (const float*)d_in[6];
    const float* aS1 = (const float*)d_in[7];
    const float* aD1 = (const float*)d_in[8];
    const float* b1  = (const float*)d_in[9];

    const int N = in_sizes[0] / 128;
    const int E = in_sizes[1] / 2;
    const int* srcp = ei;
    const int* dstp = ei + E;

    const int NB  = (N + 1023) >> 10;
    const int cap = E / NB + 4096;

    char* ws = (char*)d_ws;
    size_t off = 0;
    auto alloc = [&](size_t bytes) -> size_t {
        size_t o = off;
        off = (o + bytes + 255) & ~(size_t)255;
        return o;
    };
    __half* B1 = (__half*)(ws + alloc((size_t)N * 64 * 2));     // xw (half)
    size_t b2Bytes = (size_t)N * 64 * 2;
    size_t bkBytes = (size_t)NB * cap * 4;
    char*  region  = ws + alloc(b2Bytes > bkBytes ? b2Bytes : bkBytes);
    __half*   B2        = (__half*)region;     // hw overlays bucketBuf
    unsigned* bucketBuf = (unsigned*)region;
    float* as0 = (float*)(ws + alloc((size_t)N * 8 * 4));
    float* ad0 = (float*)(ws + alloc((size_t)N * 8 * 4));
    float* as1 = (float*)(ws + alloc((size_t)N * 4));
    float* ad1 = (float*)(ws + alloc((size_t)N * 4));
    int*   row = (int*)(ws + alloc((size_t)(N + 1) * 4));
    int*   adj = (int*)(ws + alloc((size_t)E * 4));
    int*  gcur = (int*)(ws + alloc((size_t)NB * 4));

    const int tfBlocks = (N + 63) / 64;
    const int p1Blocks = 1024;
    const int perBlock = (E + p1Blocks - 1) / p1Blocks;

    hipMemsetAsync(gcur, 0, (size_t)NB * 4, stream);
    kP1<<<tfBlocks + p1Blocks, 512, 0, stream>>>(
        x, W0, aS0, aD0, N, B1, as0, ad0, tfBlocks,
        srcp, dstp, E, p1Blocks, perBlock, bucketBuf, gcur, NB, cap);
    kP2<<<NB, 256, 0, stream>>>(bucketBuf, gcur, NB, cap, N, row, adj);

    const int agBlocks = (N + 3) / 4;
    k_agg8_tf1<<<agBlocks, 256, 0, stream>>>(B1, as0, ad0, row, adj, b0,
                                             W1, aS1, aD1, N, B2, as1, ad1);
    k_agg1<<<agBlocks, 256, 0, stream>>>(B2, as1, ad1, row, adj, b1, N, (float*)d_out);
}

// Round 9
// 484.114 us; speedup vs baseline: 1.7064x; 1.0285x over previous
//
#include <hip/hip_runtime.h>
#include <hip/hip_fp16.h>
#include <math.h>

// GAT 2-layer. R9: half2 column-pairing in agg kernels — one gather instruction
// serves 2 edges (lane = (col-pair, edge-parity)); adj prefetch per chunk.
// fp16 gather tables, fp32 accumulate. CSR via bucket sort (kP1/kP2, unchanged).

#define CAPS 32
#define STRIDE 33
#define NBMAX 128

__device__ __forceinline__ float lrelu(float v) { return v >= 0.f ? v : 0.2f * v; }
__device__ __forceinline__ float eluf(float v)  { return v > 0.f ? v : expm1f(v); }

// ---------------- transform body: 8 waves/block, 8 nodes/wave, lane = col ----
template<int K, int HEADS>
__device__ __forceinline__ void tf_body8(
    int tfb, const float* __restrict__ xin, const float* __restrict__ W,
    const float* __restrict__ attS, const float* __restrict__ attD,
    int N, __half* __restrict__ xw, float* __restrict__ as, float* __restrict__ ad,
    float* Wl)
{
    const float4* Wv = (const float4*)W;
    float4* Wlv = (float4*)Wl;
    for (int i = threadIdx.x; i < K * 16; i += 512) Wlv[i] = Wv[i];
    __syncthreads();
    int wave = threadIdx.x >> 6;
    int lane = threadIdx.x & 63;
    int n0 = tfb * 64 + wave * 8;
    if (n0 >= N) return;
    int cnt = min(8, N - n0);
    const float4* xp[8];
    #pragma unroll
    for (int j = 0; j < 8; j++)
        xp[j] = (const float4*)(xin + (size_t)(n0 + (j < cnt ? j : 0)) * K);
    float acc[8] = {0.f,0.f,0.f,0.f,0.f,0.f,0.f,0.f};
    #pragma unroll 2
    for (int k4 = 0; k4 < K / 4; k4++) {
        float4 xv[8];
        #pragma unroll
        for (int j = 0; j < 8; j++) xv[j] = xp[j][k4];
        int kb = k4 * 256 + lane;
        float w0 = Wl[kb], w1 = Wl[kb + 64], w2 = Wl[kb + 128], w3 = Wl[kb + 192];
        #pragma unroll
        for (int j = 0; j < 8; j++) {
            acc[j] = fmaf(xv[j].x, w0, acc[j]);
            acc[j] = fmaf(xv[j].y, w1, acc[j]);
            acc[j] = fmaf(xv[j].z, w2, acc[j]);
            acc[j] = fmaf(xv[j].w, w3, acc[j]);
        }
    }
    float aSl = attS[lane], aDl = attD[lane];
    #pragma unroll
    for (int j = 0; j < 8; j++) {
        if (j < cnt) {
            int n = n0 + j;
            xw[(size_t)n * 64 + lane] = __float2half(acc[j]);
            float ps = acc[j] * aSl, pd = acc[j] * aDl;
            if (HEADS == 8) {
                ps += __shfl_xor(ps, 1, 64); pd += __shfl_xor(pd, 1, 64);
                ps += __shfl_xor(ps, 2, 64); pd += __shfl_xor(pd, 2, 64);
                ps += __shfl_xor(ps, 4, 64); pd += __shfl_xor(pd, 4, 64);
                if ((lane & 7) == 0) {
                    as[(size_t)n * 8 + (lane >> 3)] = ps;
                    ad[(size_t)n * 8 + (lane >> 3)] = pd;
                }
            } else {
                #pragma unroll
                for (int off = 1; off < 64; off <<= 1) {
                    ps += __shfl_xor(ps, off, 64);
                    pd += __shfl_xor(pd, off, 64);
                }
                if (lane == 0) { as[n] = ps; ad[n] = pd; }
            }
        }
    }
}

// ---------------- fused: phase1 binning || tf0 ----------------
__global__ __launch_bounds__(512, 4) void kP1(
    const float* __restrict__ x, const float* __restrict__ W0,
    const float* __restrict__ aS, const float* __restrict__ aD,
    int N, __half* __restrict__ xw, float* __restrict__ as, float* __restrict__ ad,
    int tfBlocks,
    const int* __restrict__ src, const int* __restrict__ dst, int E,
    int p1Blocks, int perBlock,
    unsigned* __restrict__ bucketBuf, int* __restrict__ gcur, int NB, int cap)
{
    __shared__ __align__(16) char smem[128 * 64 * 4];
    int b = blockIdx.x;
    int T = tfBlocks + p1Blocks;
    int lo = (int)((long long)b * tfBlocks / T);
    int hi = (int)((long long)(b + 1) * tfBlocks / T);
    if (hi > lo) {
        tf_body8<128, 8>(lo, x, W0, aS, aD, N, xw, as, ad, (float*)smem);
    } else {
        int pb = b - hi;
        unsigned* stage = (unsigned*)smem;
        int* scnt = (int*)(smem + NBMAX * STRIDE * 4);
        int tid = threadIdx.x;
        for (int i = tid; i < NB; i += 512) scnt[i] = 0;
        __syncthreads();
        int e0 = pb * perBlock, e1 = min(E, e0 + perBlock);
        for (int base = e0; base < e1; base += 512) {
            int i = base + tid;
            if (i < e1) {
                int d = dst[i], s = src[i];
                int bk = d >> 10;
                unsigned rec = ((unsigned)(d & 1023) << 22) | (unsigned)s;
                int pos = atomicAdd(&scnt[bk], 1);
                if (pos < CAPS) {
                    stage[bk * STRIDE + pos] = rec;
                } else {
                    int g = atomicAdd(&gcur[bk], 1);
                    bucketBuf[(size_t)bk * cap + g] = rec;
                }
            }
            __syncthreads();
            if (tid < NB) {
                int n = min(scnt[tid], CAPS);
                int g16 = n & ~15;
                if (g16) {
                    int gb = atomicAdd(&gcur[tid], g16);
                    unsigned* gp = &bucketBuf[(size_t)tid * cap + gb];
                    for (int j = 0; j < g16; j++) gp[j] = stage[tid * STRIDE + j];
                    for (int j = 0; j < n - g16; j++)
                        stage[tid * STRIDE + j] = stage[tid * STRIDE + g16 + j];
                    scnt[tid] = n - g16;
                } else {
                    scnt[tid] = n;
                }
            }
            __syncthreads();
        }
        if (tid < NB) {
            int n = scnt[tid];
            if (n > 0) {
                int gb = atomicAdd(&gcur[tid], n);
                unsigned* gp = &bucketBuf[(size_t)tid * cap + gb];
                for (int j = 0; j < n; j++) gp[j] = stage[tid * STRIDE + j];
            }
        }
    }
}

// ---------------- phase2: per-bucket CSR build ----------------
__global__ __launch_bounds__(256) void kP2(
    const unsigned* __restrict__ bucketBuf, const int* __restrict__ gcur,
    int NB, int cap, int N, int* __restrict__ row, int* __restrict__ adj)
{
    __shared__ int deg[1024];
    __shared__ int curl[1024];
    __shared__ int sc[256];
    int b = blockIdx.x, tid = threadIdx.x;
    int lo = b << 10;
    int hi = min(N, lo + 1024);
    int cnt = hi - lo;
    int size = min(gcur[b], cap);
    sc[tid] = (tid < b) ? gcur[tid] : 0;
    __syncthreads();
    for (int off = 128; off > 0; off >>= 1) {
        if (tid < off) sc[tid] += sc[tid + off];
        __syncthreads();
    }
    int bbase = sc[0];
    __syncthreads();
    for (int i = tid; i < 1024; i += 256) deg[i] = 0;
    __syncthreads();
    const unsigned* buf = bucketBuf + (size_t)b * cap;
    for (int e = tid; e < size; e += 256) atomicAdd(&deg[buf[e] >> 22], 1);
    __syncthreads();
    int dv[4]; int s = 0;
    #pragma unroll
    for (int j = 0; j < 4; j++) { dv[j] = deg[tid * 4 + j]; s += dv[j]; }
    sc[tid] = s; __syncthreads();
    for (int off = 1; off < 256; off <<= 1) {
        int xv = (tid >= off) ? sc[tid - off] : 0;
        __syncthreads();
        sc[tid] += xv;
        __syncthreads();
    }
    int o = (tid ? sc[tid - 1] : 0);
    #pragma unroll
    for (int j = 0; j < 4; j++) {
        int loc = tid * 4 + j;
        curl[loc] = o;
        if (loc < cnt) row[lo + loc] = bbase + o;
        o += dv[j];
    }
    if (b == NB - 1 && tid == 0) row[N] = bbase + size;
    __syncthreads();
    for (int e = tid; e < size; e += 256) {
        unsigned r = buf[e];
        int l = r >> 22;
        int p = atomicAdd(&curl[l], 1);
        adj[bbase + p] = (int)(r & 0x3FFFFF);
    }
}

// ---------------- layer0 aggregation + fused layer1 transform ----------------
// lane = (c2 = col-pair 0..31, ep = edge parity); weight phase: lane = (e8, hh).
__global__ __launch_bounds__(256) void k_agg8_tf1(
    const __half* __restrict__ xw, const float* __restrict__ as, const float* __restrict__ ad,
    const int* __restrict__ row, const int* __restrict__ adj,
    const float* __restrict__ bias, const float* __restrict__ W1,
    const float* __restrict__ aS1, const float* __restrict__ aD1,
    int N, __half* __restrict__ hw, float* __restrict__ as1, float* __restrict__ ad1)
{
    __shared__ float Wl[64 * 64];
    {
        const float4* Wv = (const float4*)W1;
        float4* Wlv = (float4*)Wl;
        for (int i = threadIdx.x; i < 1024; i += 256) Wlv[i] = Wv[i];
    }
    __syncthreads();
    int n = (blockIdx.x * 256 + threadIdx.x) >> 6;
    int lane = threadIdx.x & 63;
    if (n >= N) return;
    int rs = row[n], re = row[n + 1];
    int hh = lane & 7;      // weight phase: head
    int e8 = lane >> 3;     // weight phase: edge-in-chunk
    int c2 = lane & 31;     // gather phase: column pair (cols 2c2, 2c2+1)
    int ep = lane >> 5;     // gather phase: edge parity
    int hq = c2 >> 2;       // head of column pair
    const __half2* xw2 = (const __half2*)xw;
    float adv = ad[(size_t)n * 8 + hh];
    float shift = lrelu(as[(size_t)n * 8 + hh] + adv);
    float2 acc;
    {
        float2 f = __half22float2(xw2[(size_t)n * 32 + c2]);  // self, w = 1
        acc.x = ep ? 0.f : f.x;
        acc.y = ep ? 0.f : f.y;
    }
    float dsum = 0.f;
    int j = rs;
    int s = (j + 8 <= re) ? adj[j + e8] : 0;   // prefetch first chunk
    for (; j + 8 <= re; ) {
        float e = lrelu(as[(size_t)s * 8 + hh] + adv);
        float w = __expf(e - shift);
        dsum += w;
        int jn = j + 8;
        int s_next = (jn + 8 <= re) ? adj[jn + e8] : 0;   // prefetch next chunk
        #pragma unroll
        for (int t = 0; t < 8; t += 2) {
            int   te = t + ep;
            float we = __shfl(w, te * 8 + hq, 64);
            int   se = __shfl(s, te * 8, 64);
            float2 xv = __half22float2(xw2[(size_t)se * 32 + c2]);
            acc.x = fmaf(we, xv.x, acc.x);
            acc.y = fmaf(we, xv.y, acc.y);
        }
        s = s_next; j = jn;
    }
    int rem = re - j;
    if (rem > 0) {
        int jj = j + e8;
        bool v = jj < re;
        int st = adj[v ? jj : rs];
        float e = lrelu(as[(size_t)st * 8 + hh] + adv);
        float w = v ? __expf(e - shift) : 0.f;
        dsum += w;
        for (int t = 0; t < rem; t += 2) {   // te==rem lanes have w=0
            int   te = t + ep;
            float we = __shfl(w, te * 8 + hq, 64);
            int   se = __shfl(st, te * 8, 64);
            float2 xv = __half22float2(xw2[(size_t)se * 32 + c2]);
            acc.x = fmaf(we, xv.x, acc.x);
            acc.y = fmaf(we, xv.y, acc.y);
        }
    }
    // combine edge-parity halves
    acc.x += __shfl_xor(acc.x, 32, 64);
    acc.y += __shfl_xor(acc.y, 32, 64);
    // denom per head (weight layout -> head sum at lane hq)
    dsum += __shfl_xor(dsum, 8, 64);
    dsum += __shfl_xor(dsum, 16, 64);
    dsum += __shfl_xor(dsum, 32, 64);
    float denom = 1.f + __shfl(dsum, hq, 64);
    float2 bi = ((const float2*)bias)[c2];
    float hx = eluf(acc.x / denom + bi.x);
    float hy = eluf(acc.y / denom + bi.y);
    // ---- fused tf1: lane = output col ----
    float a1 = 0.f;
    #pragma unroll 16
    for (int k2 = 0; k2 < 32; k2++) {
        float h0 = __shfl(hx, k2, 64);
        float h1 = __shfl(hy, k2, 64);
        a1 = fmaf(h0, Wl[(2 * k2) * 64 + lane], a1);
        a1 = fmaf(h1, Wl[(2 * k2 + 1) * 64 + lane], a1);
    }
    hw[(size_t)n * 64 + lane] = __float2half(a1);
    float ps = a1 * aS1[lane], pd = a1 * aD1[lane];
    #pragma unroll
    for (int off = 1; off < 64; off <<= 1) {
        ps += __shfl_xor(ps, off, 64);
        pd += __shfl_xor(pd, off, 64);
    }
    if (lane == 0) { as1[n] = ps; ad1[n] = pd; }
}

// ---------------- layer1 aggregation ----------------
__global__ __launch_bounds__(256) void k_agg1(
    const __half* __restrict__ hw, const float* __restrict__ as, const float* __restrict__ ad,
    const int* __restrict__ row, const int* __restrict__ adj,
    const float* __restrict__ bias, int N, float* __restrict__ outp)
{
    int n = (blockIdx.x * 256 + threadIdx.x) >> 6;
    int lane = threadIdx.x & 63;
    if (n >= N) return;
    int rs = row[n], re = row[n + 1];
    int e8 = lane >> 3;
    int c2 = lane & 31;
    int ep = lane >> 5;
    const __half2* hw2 = (const __half2*)hw;
    float adv = ad[n];
    float shift = lrelu(as[n] + adv);
    float2 acc;
    {
        float2 f = __half22float2(hw2[(size_t)n * 32 + c2]);
        acc.x = ep ? 0.f : f.x;
        acc.y = ep ? 0.f : f.y;
    }
    float dsum = 0.f;
    int j = rs;
    int s = (j + 8 <= re) ? adj[j + e8] : 0;
    for (; j + 8 <= re; ) {
        float e = lrelu(as[s] + adv);
        float w = __expf(e - shift);
        dsum += w;
        int jn = j + 8;
        int s_next = (jn + 8 <= re) ? adj[jn + e8] : 0;
        #pragma unroll
        for (int t = 0; t < 8; t += 2) {
            int   te = t + ep;
            float we = __shfl(w, te * 8, 64);
            int   se = __shfl(s, te * 8, 64);
            float2 xv = __half22float2(hw2[(size_t)se * 32 + c2]);
            acc.x = fmaf(we, xv.x, acc.x);
            acc.y = fmaf(we, xv.y, acc.y);
        }
        s = s_next; j = jn;
    }
    int rem = re - j;
    if (rem > 0) {
        int jj = j + e8;
        bool v = jj < re;
        int st = adj[v ? jj : rs];
        float e = lrelu(as[st] + adv);
        float w = v ? __expf(e - shift) : 0.f;
        dsum += w;
        for (int t = 0; t < rem; t += 2) {
            int   te = t + ep;
            float we = __shfl(w, te * 8, 64);
            int   se = __shfl(st, te * 8, 64);
            float2 xv = __half22float2(hw2[(size_t)se * 32 + c2]);
            acc.x = fmaf(we, xv.x, acc.x);
            acc.y = fmaf(we, xv.y, acc.y);
        }
    }
    acc.x += __shfl_xor(acc.x, 32, 64);
    acc.y += __shfl_xor(acc.y, 32, 64);
    dsum += __shfl_xor(dsum, 8, 64);
    dsum += __shfl_xor(dsum, 16, 64);
    dsum += __shfl_xor(dsum, 32, 64);
    float denom = 1.f + dsum;
    if (ep == 0) {
        float2 bi = ((const float2*)bias)[c2];
        float2 o;
        o.x = eluf(acc.x / denom + bi.x);
        o.y = eluf(acc.y / denom + bi.y);
        ((float2*)outp)[(size_t)n * 32 + c2] = o;
    }
}

extern "C" void kernel_launch(void* const* d_in, const int* in_sizes, int n_in,
                              void* d_out, int out_size, void* d_ws, size_t ws_size,
                              hipStream_t stream)
{
    const float* x   = (const float*)d_in[0];
    const int*   ei  = (const int*)d_in[1];
    const float* W0  = (const float*)d_in[2];
    const float* aS0 = (const float*)d_in[3];
    const float* aD0 = (const float*)d_in[4];
    const float* b0  = (const float*)d_in[5];
    const float* W1  = (const float*)d_in[6];
    const float* aS1 = (const float*)d_in[7];
    const float* aD1 = (const float*)d_in[8];
    const float* b1  = (const float*)d_in[9];

    const int N = in_sizes[0] / 128;
    const int E = in_sizes[1] / 2;
    const int* srcp = ei;
    const int* dstp = ei + E;

    const int NB  = (N + 1023) >> 10;
    const int cap = E / NB + 4096;

    char* ws = (char*)d_ws;
    size_t off = 0;
    auto alloc = [&](size_t bytes) -> size_t {
        size_t o = off;
        off = (o + bytes + 255) & ~(size_t)255;
        return o;
    };
    __half* B1 = (__half*)(ws + alloc((size_t)N * 64 * 2));     // xw (half)
    size_t b2Bytes = (size_t)N * 64 * 2;
    size_t bkBytes = (size_t)NB * cap * 4;
    char*  region  = ws + alloc(b2Bytes > bkBytes ? b2Bytes : bkBytes);
    __half*   B2        = (__half*)region;     // hw overlays bucketBuf
    unsigned* bucketBuf = (unsigned*)region;
    float* as0 = (float*)(ws + alloc((size_t)N * 8 * 4));
    float* ad0 = (float*)(ws + alloc((size_t)N * 8 * 4));
    float* as1 = (float*)(ws + alloc((size_t)N * 4));
    float* ad1 = (float*)(ws + alloc((size_t)N * 4));
    int*   row = (int*)(ws + alloc((size_t)(N + 1) * 4));
    int*   adj = (int*)(ws + alloc((size_t)E * 4));
    int*  gcur = (int*)(ws + alloc((size_t)NB * 4));

    const int tfBlocks = (N + 63) / 64;
    const int p1Blocks = 1024;
    const int perBlock = (E + p1Blocks - 1) / p1Blocks;

    hipMemsetAsync(gcur, 0, (size_t)NB * 4, stream);
    kP1<<<tfBlocks + p1Blocks, 512, 0, stream>>>(
        x, W0, aS0, aD0, N, B1, as0, ad0, tfBlocks,
        srcp, dstp, E, p1Blocks, perBlock, bucketBuf, gcur, NB, cap);
    kP2<<<NB, 256, 0, stream>>>(bucketBuf, gcur, NB, cap, N, row, adj);

    const int agBlocks = (N + 3) / 4;
    k_agg8_tf1<<<agBlocks, 256, 0, stream>>>(B1, as0, ad0, row, adj, b0,
                                             W1, aS1, aD1, N, B2, as1, ad1);
    k_agg1<<<agBlocks, 256, 0, stream>>>(B2, as1, ad1, row, adj, b1, N, (float*)d_out);
}

// Round 10
// 433.700 us; speedup vs baseline: 1.9047x; 1.1162x over previous
//
#include <hip/hip_runtime.h>
#include <hip/hip_fp16.h>
#include <math.h>

// GAT 2-layer. R10: tf1 epilogue via per-wave LDS half2 h-staging + fp16 W1 +
// v_dot2_f32_f16 (replaces 64 shfl + 64 LDS reads + 64 fma); as-gather software
// pipelining in both agg loops; tf0 unroll 4. fp16 gather tables, fp32 accum.

#define CAPS 32
#define STRIDE 33
#define NBMAX 128

typedef _Float16 h2_t __attribute__((ext_vector_type(2)));

__device__ __forceinline__ float lrelu(float v) { return v >= 0.f ? v : 0.2f * v; }
__device__ __forceinline__ float eluf(float v)  { return v > 0.f ? v : expm1f(v); }

// ---------------- transform body: 8 waves/block, 8 nodes/wave, lane = col ----
template<int K, int HEADS>
__device__ __forceinline__ void tf_body8(
    int tfb, const float* __restrict__ xin, const float* __restrict__ W,
    const float* __restrict__ attS, const float* __restrict__ attD,
    int N, __half* __restrict__ xw, float* __restrict__ as, float* __restrict__ ad,
    float* Wl)
{
    const float4* Wv = (const float4*)W;
    float4* Wlv = (float4*)Wl;
    for (int i = threadIdx.x; i < K * 16; i += 512) Wlv[i] = Wv[i];
    __syncthreads();
    int wave = threadIdx.x >> 6;
    int lane = threadIdx.x & 63;
    int n0 = tfb * 64 + wave * 8;
    if (n0 >= N) return;
    int cnt = min(8, N - n0);
    const float4* xp[8];
    #pragma unroll
    for (int j = 0; j < 8; j++)
        xp[j] = (const float4*)(xin + (size_t)(n0 + (j < cnt ? j : 0)) * K);
    float acc[8] = {0.f,0.f,0.f,0.f,0.f,0.f,0.f,0.f};
    #pragma unroll 4
    for (int k4 = 0; k4 < K / 4; k4++) {
        float4 xv[8];
        #pragma unroll
        for (int j = 0; j < 8; j++) xv[j] = xp[j][k4];
        int kb = k4 * 256 + lane;
        float w0 = Wl[kb], w1 = Wl[kb + 64], w2 = Wl[kb + 128], w3 = Wl[kb + 192];
        #pragma unroll
        for (int j = 0; j < 8; j++) {
            acc[j] = fmaf(xv[j].x, w0, acc[j]);
            acc[j] = fmaf(xv[j].y, w1, acc[j]);
            acc[j] = fmaf(xv[j].z, w2, acc[j]);
            acc[j] = fmaf(xv[j].w, w3, acc[j]);
        }
    }
    float aSl = attS[lane], aDl = attD[lane];
    #pragma unroll
    for (int j = 0; j < 8; j++) {
        if (j < cnt) {
            int n = n0 + j;
            xw[(size_t)n * 64 + lane] = __float2half(acc[j]);
            float ps = acc[j] * aSl, pd = acc[j] * aDl;
            if (HEADS == 8) {
                ps += __shfl_xor(ps, 1, 64); pd += __shfl_xor(pd, 1, 64);
                ps += __shfl_xor(ps, 2, 64); pd += __shfl_xor(pd, 2, 64);
                ps += __shfl_xor(ps, 4, 64); pd += __shfl_xor(pd, 4, 64);
                if ((lane & 7) == 0) {
                    as[(size_t)n * 8 + (lane >> 3)] = ps;
                    ad[(size_t)n * 8 + (lane >> 3)] = pd;
                }
            } else {
                #pragma unroll
                for (int off = 1; off < 64; off <<= 1) {
                    ps += __shfl_xor(ps, off, 64);
                    pd += __shfl_xor(pd, off, 64);
                }
                if (lane == 0) { as[n] = ps; ad[n] = pd; }
            }
        }
    }
}

// ---------------- fused: phase1 binning || tf0 ----------------
__global__ __launch_bounds__(512, 4) void kP1(
    const float* __restrict__ x, const float* __restrict__ W0,
    const float* __restrict__ aS, const float* __restrict__ aD,
    int N, __half* __restrict__ xw, float* __restrict__ as, float* __restrict__ ad,
    int tfBlocks,
    const int* __restrict__ src, const int* __restrict__ dst, int E,
    int p1Blocks, int perBlock,
    unsigned* __restrict__ bucketBuf, int* __restrict__ gcur, int NB, int cap)
{
    __shared__ __align__(16) char smem[128 * 64 * 4];
    int b = blockIdx.x;
    int T = tfBlocks + p1Blocks;
    int lo = (int)((long long)b * tfBlocks / T);
    int hi = (int)((long long)(b + 1) * tfBlocks / T);
    if (hi > lo) {
        tf_body8<128, 8>(lo, x, W0, aS, aD, N, xw, as, ad, (float*)smem);
    } else {
        int pb = b - hi;
        unsigned* stage = (unsigned*)smem;
        int* scnt = (int*)(smem + NBMAX * STRIDE * 4);
        int tid = threadIdx.x;
        for (int i = tid; i < NB; i += 512) scnt[i] = 0;
        __syncthreads();
        int e0 = pb * perBlock, e1 = min(E, e0 + perBlock);
        for (int base = e0; base < e1; base += 512) {
            int i = base + tid;
            if (i < e1) {
                int d = dst[i], s = src[i];
                int bk = d >> 10;
                unsigned rec = ((unsigned)(d & 1023) << 22) | (unsigned)s;
                int pos = atomicAdd(&scnt[bk], 1);
                if (pos < CAPS) {
                    stage[bk * STRIDE + pos] = rec;
                } else {
                    int g = atomicAdd(&gcur[bk], 1);
                    bucketBuf[(size_t)bk * cap + g] = rec;
                }
            }
            __syncthreads();
            if (tid < NB) {
                int n = min(scnt[tid], CAPS);
                int g16 = n & ~15;
                if (g16) {
                    int gb = atomicAdd(&gcur[tid], g16);
                    unsigned* gp = &bucketBuf[(size_t)tid * cap + gb];
                    for (int j = 0; j < g16; j++) gp[j] = stage[tid * STRIDE + j];
                    for (int j = 0; j < n - g16; j++)
                        stage[tid * STRIDE + j] = stage[tid * STRIDE + g16 + j];
                    scnt[tid] = n - g16;
                } else {
                    scnt[tid] = n;
                }
            }
            __syncthreads();
        }
        if (tid < NB) {
            int n = scnt[tid];
            if (n > 0) {
                int gb = atomicAdd(&gcur[tid], n);
                unsigned* gp = &bucketBuf[(size_t)tid * cap + gb];
                for (int j = 0; j < n; j++) gp[j] = stage[tid * STRIDE + j];
            }
        }
    }
}

// ---------------- phase2: per-bucket CSR build ----------------
__global__ __launch_bounds__(256) void kP2(
    const unsigned* __restrict__ bucketBuf, const int* __restrict__ gcur,
    int NB, int cap, int N, int* __restrict__ row, int* __restrict__ adj)
{
    __shared__ int deg[1024];
    __shared__ int curl[1024];
    __shared__ int sc[256];
    int b = blockIdx.x, tid = threadIdx.x;
    int lo = b << 10;
    int hi = min(N, lo + 1024);
    int cnt = hi - lo;
    int size = min(gcur[b], cap);
    sc[tid] = (tid < b) ? gcur[tid] : 0;
    __syncthreads();
    for (int off = 128; off > 0; off >>= 1) {
        if (tid < off) sc[tid] += sc[tid + off];
        __syncthreads();
    }
    int bbase = sc[0];
    __syncthreads();
    for (int i = tid; i < 1024; i += 256) deg[i] = 0;
    __syncthreads();
    const unsigned* buf = bucketBuf + (size_t)b * cap;
    for (int e = tid; e < size; e += 256) atomicAdd(&deg[buf[e] >> 22], 1);
    __syncthreads();
    int dv[4]; int s = 0;
    #pragma unroll
    for (int j = 0; j < 4; j++) { dv[j] = deg[tid * 4 + j]; s += dv[j]; }
    sc[tid] = s; __syncthreads();
    for (int off = 1; off < 256; off <<= 1) {
        int xv = (tid >= off) ? sc[tid - off] : 0;
        __syncthreads();
        sc[tid] += xv;
        __syncthreads();
    }
    int o = (tid ? sc[tid - 1] : 0);
    #pragma unroll
    for (int j = 0; j < 4; j++) {
        int loc = tid * 4 + j;
        curl[loc] = o;
        if (loc < cnt) row[lo + loc] = bbase + o;
        o += dv[j];
    }
    if (b == NB - 1 && tid == 0) row[N] = bbase + size;
    __syncthreads();
    for (int e = tid; e < size; e += 256) {
        unsigned r = buf[e];
        int l = r >> 22;
        int p = atomicAdd(&curl[l], 1);
        adj[bbase + p] = (int)(r & 0x3FFFFF);
    }
}

// ---------------- layer0 aggregation + fused layer1 transform ----------------
// gather phase: lane = (c2 = col-pair 0..31, ep = edge parity); weight: (e8, hh).
__global__ __launch_bounds__(256) void k_agg8_tf1(
    const __half* __restrict__ xw, const float* __restrict__ as, const float* __restrict__ ad,
    const int* __restrict__ row, const int* __restrict__ adj,
    const float* __restrict__ bias, const float* __restrict__ W1,
    const float* __restrict__ aS1, const float* __restrict__ aD1,
    int N, __half* __restrict__ hw, float* __restrict__ as1, float* __restrict__ ad1)
{
    __shared__ h2_t Wl2[32 * 64];     // W1 as half2 k-pairs: Wl2[k2*64+c] = (W1[2k2][c], W1[2k2+1][c])
    __shared__ h2_t hst[4 * 32];      // per-wave h staging (32 col-pairs)
    for (int i = threadIdx.x; i < 32 * 64; i += 256) {
        int k2 = i >> 6, c = i & 63;
        h2_t v;
        v.x = (_Float16)W1[(2 * k2) * 64 + c];
        v.y = (_Float16)W1[(2 * k2 + 1) * 64 + c];
        Wl2[i] = v;
    }
    __syncthreads();
    int wv = threadIdx.x >> 6;
    int n = (blockIdx.x * 256 + threadIdx.x) >> 6;
    int lane = threadIdx.x & 63;
    if (n >= N) return;
    int rs = row[n], re = row[n + 1];
    int hh = lane & 7;      // weight phase: head
    int e8 = lane >> 3;     // weight phase: edge-in-chunk
    int c2 = lane & 31;     // gather phase: column pair
    int ep = lane >> 5;     // gather phase: edge parity
    int hq = c2 >> 2;       // head of column pair
    const __half2* xw2 = (const __half2*)xw;
    float adv = ad[(size_t)n * 8 + hh];
    float shift = lrelu(as[(size_t)n * 8 + hh] + adv);
    float2 acc;
    {
        float2 f = __half22float2(xw2[(size_t)n * 32 + c2]);  // self, w = 1
        acc.x = ep ? 0.f : f.x;
        acc.y = ep ? 0.f : f.y;
    }
    float dsum = 0.f;
    int j = rs;
    bool have = (j + 8 <= re);
    int   sC = have ? adj[j + e8] : 0;
    float eC = have ? lrelu(as[(size_t)sC * 8 + hh] + adv) : 0.f;
    while (have) {
        int jn = j + 8;
        bool haveN = (jn + 8 <= re);
        int sN = haveN ? adj[jn + e8] : 0;                           // prefetch adj
        float w = __expf(eC - shift);
        dsum += w;
        float eN = haveN ? lrelu(as[(size_t)sN * 8 + hh] + adv) : 0.f; // prefetch logit
        #pragma unroll
        for (int t = 0; t < 8; t += 2) {
            int   te = t + ep;
            float we = __shfl(w, te * 8 + hq, 64);
            int   se = __shfl(sC, te * 8, 64);
            float2 xv = __half22float2(xw2[(size_t)se * 32 + c2]);
            acc.x = fmaf(we, xv.x, acc.x);
            acc.y = fmaf(we, xv.y, acc.y);
        }
        sC = sN; eC = eN; j = jn; have = haveN;
    }
    int rem = re - j;
    if (rem > 0) {
        int jj = j + e8;
        bool v = jj < re;
        int st = adj[v ? jj : rs];
        float e = lrelu(as[(size_t)st * 8 + hh] + adv);
        float w = v ? __expf(e - shift) : 0.f;
        dsum += w;
        for (int t = 0; t < rem; t += 2) {
            int   te = t + ep;
            float we = __shfl(w, te * 8 + hq, 64);
            int   se = __shfl(st, te * 8, 64);
            float2 xv = __half22float2(xw2[(size_t)se * 32 + c2]);
            acc.x = fmaf(we, xv.x, acc.x);
            acc.y = fmaf(we, xv.y, acc.y);
        }
    }
    acc.x += __shfl_xor(acc.x, 32, 64);
    acc.y += __shfl_xor(acc.y, 32, 64);
    dsum += __shfl_xor(dsum, 8, 64);
    dsum += __shfl_xor(dsum, 16, 64);
    dsum += __shfl_xor(dsum, 32, 64);
    float denom = 1.f + __shfl(dsum, hq, 64);
    float2 bi = ((const float2*)bias)[c2];
    float hx = eluf(acc.x / denom + bi.x);
    float hy = eluf(acc.y / denom + bi.y);
    // ---- fused tf1 via LDS h-staging + fp16 dot2 ----
    if (ep == 0) {
        h2_t hv;
        hv.x = (_Float16)hx;
        hv.y = (_Float16)hy;
        hst[wv * 32 + c2] = hv;
    }
    float a1 = 0.f;
    #pragma unroll
    for (int k2 = 0; k2 < 32; k2++) {
        h2_t hp = hst[wv * 32 + k2];     // broadcast read
        h2_t wp = Wl2[k2 * 64 + lane];   // conflict-free (2-way)
        a1 = __builtin_amdgcn_fdot2(hp, wp, a1, false);
    }
    hw[(size_t)n * 64 + lane] = __float2half(a1);
    float ps = a1 * aS1[lane], pd = a1 * aD1[lane];
    #pragma unroll
    for (int off = 1; off < 64; off <<= 1) {
        ps += __shfl_xor(ps, off, 64);
        pd += __shfl_xor(pd, off, 64);
    }
    if (lane == 0) { as1[n] = ps; ad1[n] = pd; }
}

// ---------------- layer1 aggregation ----------------
__global__ __launch_bounds__(256) void k_agg1(
    const __half* __restrict__ hw, const float* __restrict__ as, const float* __restrict__ ad,
    const int* __restrict__ row, const int* __restrict__ adj,
    const float* __restrict__ bias, int N, float* __restrict__ outp)
{
    int n = (blockIdx.x * 256 + threadIdx.x) >> 6;
    int lane = threadIdx.x & 63;
    if (n >= N) return;
    int rs = row[n], re = row[n + 1];
    int e8 = lane >> 3;
    int c2 = lane & 31;
    int ep = lane >> 5;
    const __half2* hw2 = (const __half2*)hw;
    float adv = ad[n];
    float shift = lrelu(as[n] + adv);
    float2 acc;
    {
        float2 f = __half22float2(hw2[(size_t)n * 32 + c2]);
        acc.x = ep ? 0.f : f.x;
        acc.y = ep ? 0.f : f.y;
    }
    float dsum = 0.f;
    int j = rs;
    bool have = (j + 8 <= re);
    int   sC = have ? adj[j + e8] : 0;
    float eC = have ? lrelu(as[sC] + adv) : 0.f;
    while (have) {
        int jn = j + 8;
        bool haveN = (jn + 8 <= re);
        int sN = haveN ? adj[jn + e8] : 0;
        float w = __expf(eC - shift);
        dsum += w;
        float eN = haveN ? lrelu(as[sN] + adv) : 0.f;
        #pragma unroll
        for (int t = 0; t < 8; t += 2) {
            int   te = t + ep;
            float we = __shfl(w, te * 8, 64);
            int   se = __shfl(sC, te * 8, 64);
            float2 xv = __half22float2(hw2[(size_t)se * 32 + c2]);
            acc.x = fmaf(we, xv.x, acc.x);
            acc.y = fmaf(we, xv.y, acc.y);
        }
        sC = sN; eC = eN; j = jn; have = haveN;
    }
    int rem = re - j;
    if (rem > 0) {
        int jj = j + e8;
        bool v = jj < re;
        int st = adj[v ? jj : rs];
        float e = lrelu(as[st] + adv);
        float w = v ? __expf(e - shift) : 0.f;
        dsum += w;
        for (int t = 0; t < rem; t += 2) {
            int   te = t + ep;
            float we = __shfl(w, te * 8, 64);
            int   se = __shfl(st, te * 8, 64);
            float2 xv = __half22float2(hw2[(size_t)se * 32 + c2]);
            acc.x = fmaf(we, xv.x, acc.x);
            acc.y = fmaf(we, xv.y, acc.y);
        }
    }
    acc.x += __shfl_xor(acc.x, 32, 64);
    acc.y += __shfl_xor(acc.y, 32, 64);
    dsum += __shfl_xor(dsum, 8, 64);
    dsum += __shfl_xor(dsum, 16, 64);
    dsum += __shfl_xor(dsum, 32, 64);
    float denom = 1.f + dsum;
    if (ep == 0) {
        float2 bi = ((const float2*)bias)[c2];
        float2 o;
        o.x = eluf(acc.x / denom + bi.x);
        o.y = eluf(acc.y / denom + bi.y);
        ((float2*)outp)[(size_t)n * 32 + c2] = o;
    }
}

extern "C" void kernel_launch(void* const* d_in, const int* in_sizes, int n_in,
                              void* d_out, int out_size, void* d_ws, size_t ws_size,
                              hipStream_t stream)
{
    const float* x   = (const float*)d_in[0];
    const int*   ei  = (const int*)d_in[1];
    const float* W0  = (const float*)d_in[2];
    const float* aS0 = (const float*)d_in[3];
    const float* aD0 = (const float*)d_in[4];
    const float* b0  = (const float*)d_in[5];
    const float* W1  = (const float*)d_in[6];
    const float* aS1 = (const float*)d_in[7];
    const float* aD1 = (const float*)d_in[8];
    const float* b1  = (const float*)d_in[9];

    const int N = in_sizes[0] / 128;
    const int E = in_sizes[1] / 2;
    const int* srcp = ei;
    const int* dstp = ei + E;

    const int NB  = (N + 1023) >> 10;
    const int cap = E / NB + 4096;

    char* ws = (char*)d_ws;
    size_t off = 0;
    auto alloc = [&](size_t bytes) -> size_t {
        size_t o = off;
        off = (o + bytes + 255) & ~(size_t)255;
        return o;
    };
    __half* B1 = (__half*)(ws + alloc((size_t)N * 64 * 2));     // xw (half)
    size_t b2Bytes = (size_t)N * 64 * 2;
    size_t bkBytes = (size_t)NB * cap * 4;
    char*  region  = ws + alloc(b2Bytes > bkBytes ? b2Bytes : bkBytes);
    __half*   B2        = (__half*)region;     // hw overlays bucketBuf
    unsigned* bucketBuf = (unsigned*)region;
    float* as0 = (float*)(ws + alloc((size_t)N * 8 * 4));
    float* ad0 = (float*)(ws + alloc((size_t)N * 8 * 4));
    float* as1 = (float*)(ws + alloc((size_t)N * 4));
    float* ad1 = (float*)(ws + alloc((size_t)N * 4));
    int*   row = (int*)(ws + alloc((size_t)(N + 1) * 4));
    int*   adj = (int*)(ws + alloc((size_t)E * 4));
    int*  gcur = (int*)(ws + alloc((size_t)NB * 4));

    const int tfBlocks = (N + 63) / 64;
    const int p1Blocks = 1024;
    const int perBlock = (E + p1Blocks - 1) / p1Blocks;

    hipMemsetAsync(gcur, 0, (size_t)NB * 4, stream);
    kP1<<<tfBlocks + p1Blocks, 512, 0, stream>>>(
        x, W0, aS0, aD0, N, B1, as0, ad0, tfBlocks,
        srcp, dstp, E, p1Blocks, perBlock, bucketBuf, gcur, NB, cap);
    kP2<<<NB, 256, 0, stream>>>(bucketBuf, gcur, NB, cap, N, row, adj);

    const int agBlocks = (N + 3) / 4;
    k_agg8_tf1<<<agBlocks, 256, 0, stream>>>(B1, as0, ad0, row, adj, b0,
                                             W1, aS1, aD1, N, B2, as1, ad1);
    k_agg1<<<agBlocks, 256, 0, stream>>>(B2, as1, ad1, row, adj, b1, N, (float*)d_out);
}

// Round 11
// 385.283 us; speedup vs baseline: 2.1441x; 1.1257x over previous
//
#include <hip/hip_runtime.h>
#include <hip/hip_fp16.h>
#include <math.h>

// GAT 2-layer. R11: tf0 replaced by MFMA fp16 GEMM [N,128]@[128,80] with att
// reductions folded as 16 extra B-columns (W0@AS | W0@AD); B pre-swizzled by
// kPrep for conflict-free ds_read_b128 fragments. Binning now standalone (kBin).
// Agg kernels unchanged from R10.

#define CAPS 32
#define STRIDE 33
#define NBMAX 128

typedef _Float16 h2_t  __attribute__((ext_vector_type(2)));
typedef _Float16 h8_t  __attribute__((ext_vector_type(8)));
typedef float    f4_t  __attribute__((ext_vector_type(4)));

__device__ __forceinline__ float lrelu(float v) { return v >= 0.f ? v : 0.2f * v; }
__device__ __forceinline__ float eluf(float v)  { return v > 0.f ? v : expm1f(v); }

// ---------------- prep: build swizzled fp16 B-image [ct][ks][quad][col][j] ----
// k = ks*32 + quad*8 + j ; global col = ct*16 + col. ct==4: cols = W0@AS | W0@AD.
__global__ void kPrep(const float* __restrict__ W0,
                      const float* __restrict__ aS0, const float* __restrict__ aD0,
                      __half* __restrict__ W0swz)
{
    for (int g = threadIdx.x; g < 1280; g += 256) {
        int col  = g & 15;
        int quad = (g >> 4) & 3;
        int ks   = (g >> 6) & 3;
        int ct   = g >> 8;
        #pragma unroll
        for (int j = 0; j < 8; j++) {
            int k = ks * 32 + quad * 8 + j;
            float v;
            if (ct < 4) {
                v = W0[k * 64 + ct * 16 + col];
            } else {
                int h = col & 7;
                const float* att = (col < 8) ? aS0 : aD0;
                v = 0.f;
                #pragma unroll
                for (int cc = 0; cc < 8; cc++)
                    v += W0[k * 64 + h * 8 + cc] * att[h * 8 + cc];
            }
            W0swz[g * 8 + j] = __float2half(v);
        }
    }
}

// ---------------- tf0 via MFMA: 4 waves/block, 16 rows/wave ----------------
__global__ __launch_bounds__(256) void kGemm0(
    const float* __restrict__ x, const __half* __restrict__ W0swz,
    int N, __half* __restrict__ xw, float* __restrict__ as, float* __restrict__ ad)
{
    __shared__ h8_t Bl[1280];   // 20.5 KB
    {
        const float4* s = (const float4*)W0swz;
        float4* d = (float4*)Bl;
        for (int i = threadIdx.x; i < 1280; i += 256) d[i] = s[i];
    }
    __syncthreads();
    int wave = threadIdx.x >> 6, lane = threadIdx.x & 63;
    int row0 = blockIdx.x * 64 + wave * 16;
    if (row0 >= N) return;
    int quad = lane >> 4, c16 = lane & 15;
    int myrow = min(row0 + c16, N - 1);
    const float* xr = x + (size_t)myrow * 128;
    h8_t a[4];
    #pragma unroll
    for (int ks = 0; ks < 4; ks++) {
        int kb = ks * 32 + quad * 8;
        float4 v0 = *(const float4*)(xr + kb);
        float4 v1 = *(const float4*)(xr + kb + 4);
        h8_t av;
        av[0] = (_Float16)v0.x; av[1] = (_Float16)v0.y;
        av[2] = (_Float16)v0.z; av[3] = (_Float16)v0.w;
        av[4] = (_Float16)v1.x; av[5] = (_Float16)v1.y;
        av[6] = (_Float16)v1.z; av[7] = (_Float16)v1.w;
        a[ks] = av;
    }
    int rbase = row0 + quad * 4;   // C/D: row = quad*4 + reg, col = c16
    #pragma unroll
    for (int ct = 0; ct < 5; ct++) {
        f4_t acc = {0.f, 0.f, 0.f, 0.f};
        #pragma unroll
        for (int ks = 0; ks < 4; ks++) {
            h8_t b = Bl[(ct * 4 + ks) * 64 + lane];
            acc = __builtin_amdgcn_mfma_f32_16x16x32_f16(a[ks], b, acc, 0, 0, 0);
        }
        if (ct < 4) {
            int col = ct * 16 + c16;
            #pragma unroll
            for (int r = 0; r < 4; r++) {
                int row = rbase + r;
                if (row < N) xw[(size_t)row * 64 + col] = __float2half(acc[r]);
            }
        } else {
            #pragma unroll
            for (int r = 0; r < 4; r++) {
                int row = rbase + r;
                if (row < N) {
                    if (c16 < 8) as[(size_t)row * 8 + c16] = acc[r];
                    else         ad[(size_t)row * 8 + (c16 - 8)] = acc[r];
                }
            }
        }
    }
}

// ---------------- binning (standalone; R10-proven code path) ----------------
__global__ __launch_bounds__(512) void kBin(
    const int* __restrict__ src, const int* __restrict__ dst, int E, int perBlock,
    unsigned* __restrict__ bucketBuf, int* __restrict__ gcur, int NB, int cap)
{
    __shared__ unsigned stage[NBMAX * STRIDE];
    __shared__ int scnt[NBMAX];
    int pb = blockIdx.x;
    int tid = threadIdx.x;
    for (int i = tid; i < NB; i += 512) scnt[i] = 0;
    __syncthreads();
    int e0 = pb * perBlock, e1 = min(E, e0 + perBlock);
    for (int base = e0; base < e1; base += 512) {
        int i = base + tid;
        if (i < e1) {
            int d = dst[i], s = src[i];
            int bk = d >> 10;
            unsigned rec = ((unsigned)(d & 1023) << 22) | (unsigned)s;
            int pos = atomicAdd(&scnt[bk], 1);
            if (pos < CAPS) {
                stage[bk * STRIDE + pos] = rec;
            } else {
                int g = atomicAdd(&gcur[bk], 1);
                bucketBuf[(size_t)bk * cap + g] = rec;
            }
        }
        __syncthreads();
        if (tid < NB) {
            int n = min(scnt[tid], CAPS);
            int g16 = n & ~15;
            if (g16) {
                int gb = atomicAdd(&gcur[tid], g16);
                unsigned* gp = &bucketBuf[(size_t)tid * cap + gb];
                for (int j = 0; j < g16; j++) gp[j] = stage[tid * STRIDE + j];
                for (int j = 0; j < n - g16; j++)
                    stage[tid * STRIDE + j] = stage[tid * STRIDE + g16 + j];
                scnt[tid] = n - g16;
            } else {
                scnt[tid] = n;
            }
        }
        __syncthreads();
    }
    if (tid < NB) {
        int n = scnt[tid];
        if (n > 0) {
            int gb = atomicAdd(&gcur[tid], n);
            unsigned* gp = &bucketBuf[(size_t)tid * cap + gb];
            for (int j = 0; j < n; j++) gp[j] = stage[tid * STRIDE + j];
        }
    }
}

// ---------------- phase2: per-bucket CSR build ----------------
__global__ __launch_bounds__(256) void kP2(
    const unsigned* __restrict__ bucketBuf, const int* __restrict__ gcur,
    int NB, int cap, int N, int* __restrict__ row, int* __restrict__ adj)
{
    __shared__ int deg[1024];
    __shared__ int curl[1024];
    __shared__ int sc[256];
    int b = blockIdx.x, tid = threadIdx.x;
    int lo = b << 10;
    int hi = min(N, lo + 1024);
    int cnt = hi - lo;
    int size = min(gcur[b], cap);
    sc[tid] = (tid < b) ? gcur[tid] : 0;
    __syncthreads();
    for (int off = 128; off > 0; off >>= 1) {
        if (tid < off) sc[tid] += sc[tid + off];
        __syncthreads();
    }
    int bbase = sc[0];
    __syncthreads();
    for (int i = tid; i < 1024; i += 256) deg[i] = 0;
    __syncthreads();
    const unsigned* buf = bucketBuf + (size_t)b * cap;
    for (int e = tid; e < size; e += 256) atomicAdd(&deg[buf[e] >> 22], 1);
    __syncthreads();
    int dv[4]; int s = 0;
    #pragma unroll
    for (int j = 0; j < 4; j++) { dv[j] = deg[tid * 4 + j]; s += dv[j]; }
    sc[tid] = s; __syncthreads();
    for (int off = 1; off < 256; off <<= 1) {
        int xv = (tid >= off) ? sc[tid - off] : 0;
        __syncthreads();
        sc[tid] += xv;
        __syncthreads();
    }
    int o = (tid ? sc[tid - 1] : 0);
    #pragma unroll
    for (int j = 0; j < 4; j++) {
        int loc = tid * 4 + j;
        curl[loc] = o;
        if (loc < cnt) row[lo + loc] = bbase + o;
        o += dv[j];
    }
    if (b == NB - 1 && tid == 0) row[N] = bbase + size;
    __syncthreads();
    for (int e = tid; e < size; e += 256) {
        unsigned r = buf[e];
        int l = r >> 22;
        int p = atomicAdd(&curl[l], 1);
        adj[bbase + p] = (int)(r & 0x3FFFFF);
    }
}

// ---------------- layer0 aggregation + fused layer1 transform ----------------
__global__ __launch_bounds__(256) void k_agg8_tf1(
    const __half* __restrict__ xw, const float* __restrict__ as, const float* __restrict__ ad,
    const int* __restrict__ row, const int* __restrict__ adj,
    const float* __restrict__ bias, const float* __restrict__ W1,
    const float* __restrict__ aS1, const float* __restrict__ aD1,
    int N, __half* __restrict__ hw, float* __restrict__ as1, float* __restrict__ ad1)
{
    __shared__ h2_t Wl2[32 * 64];
    __shared__ h2_t hst[4 * 32];
    for (int i = threadIdx.x; i < 32 * 64; i += 256) {
        int k2 = i >> 6, c = i & 63;
        h2_t v;
        v.x = (_Float16)W1[(2 * k2) * 64 + c];
        v.y = (_Float16)W1[(2 * k2 + 1) * 64 + c];
        Wl2[i] = v;
    }
    __syncthreads();
    int wv = threadIdx.x >> 6;
    int n = (blockIdx.x * 256 + threadIdx.x) >> 6;
    int lane = threadIdx.x & 63;
    if (n >= N) return;
    int rs = row[n], re = row[n + 1];
    int hh = lane & 7;
    int e8 = lane >> 3;
    int c2 = lane & 31;
    int ep = lane >> 5;
    int hq = c2 >> 2;
    const __half2* xw2 = (const __half2*)xw;
    float adv = ad[(size_t)n * 8 + hh];
    float shift = lrelu(as[(size_t)n * 8 + hh] + adv);
    float2 acc;
    {
        float2 f = __half22float2(xw2[(size_t)n * 32 + c2]);
        acc.x = ep ? 0.f : f.x;
        acc.y = ep ? 0.f : f.y;
    }
    float dsum = 0.f;
    int j = rs;
    bool have = (j + 8 <= re);
    int   sC = have ? adj[j + e8] : 0;
    float eC = have ? lrelu(as[(size_t)sC * 8 + hh] + adv) : 0.f;
    while (have) {
        int jn = j + 8;
        bool haveN = (jn + 8 <= re);
        int sN = haveN ? adj[jn + e8] : 0;
        float w = __expf(eC - shift);
        dsum += w;
        float eN = haveN ? lrelu(as[(size_t)sN * 8 + hh] + adv) : 0.f;
        #pragma unroll
        for (int t = 0; t < 8; t += 2) {
            int   te = t + ep;
            float we = __shfl(w, te * 8 + hq, 64);
            int   se = __shfl(sC, te * 8, 64);
            float2 xv = __half22float2(xw2[(size_t)se * 32 + c2]);
            acc.x = fmaf(we, xv.x, acc.x);
            acc.y = fmaf(we, xv.y, acc.y);
        }
        sC = sN; eC = eN; j = jn; have = haveN;
    }
    int rem = re - j;
    if (rem > 0) {
        int jj = j + e8;
        bool v = jj < re;
        int st = adj[v ? jj : rs];
        float e = lrelu(as[(size_t)st * 8 + hh] + adv);
        float w = v ? __expf(e - shift) : 0.f;
        dsum += w;
        for (int t = 0; t < rem; t += 2) {
            int   te = t + ep;
            float we = __shfl(w, te * 8 + hq, 64);
            int   se = __shfl(st, te * 8, 64);
            float2 xv = __half22float2(xw2[(size_t)se * 32 + c2]);
            acc.x = fmaf(we, xv.x, acc.x);
            acc.y = fmaf(we, xv.y, acc.y);
        }
    }
    acc.x += __shfl_xor(acc.x, 32, 64);
    acc.y += __shfl_xor(acc.y, 32, 64);
    dsum += __shfl_xor(dsum, 8, 64);
    dsum += __shfl_xor(dsum, 16, 64);
    dsum += __shfl_xor(dsum, 32, 64);
    float denom = 1.f + __shfl(dsum, hq, 64);
    float2 bi = ((const float2*)bias)[c2];
    float hx = eluf(acc.x / denom + bi.x);
    float hy = eluf(acc.y / denom + bi.y);
    if (ep == 0) {
        h2_t hv;
        hv.x = (_Float16)hx;
        hv.y = (_Float16)hy;
        hst[wv * 32 + c2] = hv;
    }
    float a1 = 0.f;
    #pragma unroll
    for (int k2 = 0; k2 < 32; k2++) {
        h2_t hp = hst[wv * 32 + k2];
        h2_t wp = Wl2[k2 * 64 + lane];
        a1 = __builtin_amdgcn_fdot2(hp, wp, a1, false);
    }
    hw[(size_t)n * 64 + lane] = __float2half(a1);
    float ps = a1 * aS1[lane], pd = a1 * aD1[lane];
    #pragma unroll
    for (int off = 1; off < 64; off <<= 1) {
        ps += __shfl_xor(ps, off, 64);
        pd += __shfl_xor(pd, off, 64);
    }
    if (lane == 0) { as1[n] = ps; ad1[n] = pd; }
}

// ---------------- layer1 aggregation ----------------
__global__ __launch_bounds__(256) void k_agg1(
    const __half* __restrict__ hw, const float* __restrict__ as, const float* __restrict__ ad,
    const int* __restrict__ row, const int* __restrict__ adj,
    const float* __restrict__ bias, int N, float* __restrict__ outp)
{
    int n = (blockIdx.x * 256 + threadIdx.x) >> 6;
    int lane = threadIdx.x & 63;
    if (n >= N) return;
    int rs = row[n], re = row[n + 1];
    int e8 = lane >> 3;
    int c2 = lane & 31;
    int ep = lane >> 5;
    const __half2* hw2 = (const __half2*)hw;
    float adv = ad[n];
    float shift = lrelu(as[n] + adv);
    float2 acc;
    {
        float2 f = __half22float2(hw2[(size_t)n * 32 + c2]);
        acc.x = ep ? 0.f : f.x;
        acc.y = ep ? 0.f : f.y;
    }
    float dsum = 0.f;
    int j = rs;
    bool have = (j + 8 <= re);
    int   sC = have ? adj[j + e8] : 0;
    float eC = have ? lrelu(as[sC] + adv) : 0.f;
    while (have) {
        int jn = j + 8;
        bool haveN = (jn + 8 <= re);
        int sN = haveN ? adj[jn + e8] : 0;
        float w = __expf(eC - shift);
        dsum += w;
        float eN = haveN ? lrelu(as[sN] + adv) : 0.f;
        #pragma unroll
        for (int t = 0; t < 8; t += 2) {
            int   te = t + ep;
            float we = __shfl(w, te * 8, 64);
            int   se = __shfl(sC, te * 8, 64);
            float2 xv = __half22float2(hw2[(size_t)se * 32 + c2]);
            acc.x = fmaf(we, xv.x, acc.x);
            acc.y = fmaf(we, xv.y, acc.y);
        }
        sC = sN; eC = eN; j = jn; have = haveN;
    }
    int rem = re - j;
    if (rem > 0) {
        int jj = j + e8;
        bool v = jj < re;
        int st = adj[v ? jj : rs];
        float e = lrelu(as[st] + adv);
        float w = v ? __expf(e - shift) : 0.f;
        dsum += w;
        for (int t = 0; t < rem; t += 2) {
            int   te = t + ep;
            float we = __shfl(w, te * 8, 64);
            int   se = __shfl(st, te * 8, 64);
            float2 xv = __half22float2(hw2[(size_t)se * 32 + c2]);
            acc.x = fmaf(we, xv.x, acc.x);
            acc.y = fmaf(we, xv.y, acc.y);
        }
    }
    acc.x += __shfl_xor(acc.x, 32, 64);
    acc.y += __shfl_xor(acc.y, 32, 64);
    dsum += __shfl_xor(dsum, 8, 64);
    dsum += __shfl_xor(dsum, 16, 64);
    dsum += __shfl_xor(dsum, 32, 64);
    float denom = 1.f + dsum;
    if (ep == 0) {
        float2 bi = ((const float2*)bias)[c2];
        float2 o;
        o.x = eluf(acc.x / denom + bi.x);
        o.y = eluf(acc.y / denom + bi.y);
        ((float2*)outp)[(size_t)n * 32 + c2] = o;
    }
}

extern "C" void kernel_launch(void* const* d_in, const int* in_sizes, int n_in,
                              void* d_out, int out_size, void* d_ws, size_t ws_size,
                              hipStream_t stream)
{
    const float* x   = (const float*)d_in[0];
    const int*   ei  = (const int*)d_in[1];
    const float* W0  = (const float*)d_in[2];
    const float* aS0 = (const float*)d_in[3];
    const float* aD0 = (const float*)d_in[4];
    const float* b0  = (const float*)d_in[5];
    const float* W1  = (const float*)d_in[6];
    const float* aS1 = (const float*)d_in[7];
    const float* aD1 = (const float*)d_in[8];
    const float* b1  = (const float*)d_in[9];

    const int N = in_sizes[0] / 128;
    const int E = in_sizes[1] / 2;
    const int* srcp = ei;
    const int* dstp = ei + E;

    const int NB  = (N + 1023) >> 10;
    const int cap = E / NB + 4096;

    char* ws = (char*)d_ws;
    size_t off = 0;
    auto alloc = [&](size_t bytes) -> size_t {
        size_t o = off;
        off = (o + bytes + 255) & ~(size_t)255;
        return o;
    };
    __half* B1 = (__half*)(ws + alloc((size_t)N * 64 * 2));     // xw (half)
    size_t b2Bytes = (size_t)N * 64 * 2;
    size_t bkBytes = (size_t)NB * cap * 4;
    char*  region  = ws + alloc(b2Bytes > bkBytes ? b2Bytes : bkBytes);
    __half*   B2        = (__half*)region;     // hw overlays bucketBuf
    unsigned* bucketBuf = (unsigned*)region;
    float* as0 = (float*)(ws + alloc((size_t)N * 8 * 4));
    float* ad0 = (float*)(ws + alloc((size_t)N * 8 * 4));
    float* as1 = (float*)(ws + alloc((size_t)N * 4));
    float* ad1 = (float*)(ws + alloc((size_t)N * 4));
    int*   row = (int*)(ws + alloc((size_t)(N + 1) * 4));
    int*   adj = (int*)(ws + alloc((size_t)E * 4));
    int*  gcur = (int*)(ws + alloc((size_t)NB * 4));
    __half* W0swz = (__half*)(ws + alloc(1280 * 8 * 2));

    const int p1Blocks = 1024;
    const int perBlock = (E + p1Blocks - 1) / p1Blocks;

    hipMemsetAsync(gcur, 0, (size_t)NB * 4, stream);
    kPrep<<<1, 256, 0, stream>>>(W0, aS0, aD0, W0swz);
    kBin<<<p1Blocks, 512, 0, stream>>>(srcp, dstp, E, perBlock, bucketBuf, gcur, NB, cap);
    kGemm0<<<(N + 63) / 64, 256, 0, stream>>>(x, W0swz, N, B1, as0, ad0);
    kP2<<<NB, 256, 0, stream>>>(bucketBuf, gcur, NB, cap, N, row, adj);

    const int agBlocks = (N + 3) / 4;
    k_agg8_tf1<<<agBlocks, 256, 0, stream>>>(B1, as0, ad0, row, adj, b0,
                                             W1, aS1, aD1, N, B2, as1, ad1);
    k_agg1<<<agBlocks, 256, 0, stream>>>(B2, as1, ad1, row, adj, b1, N, (float*)d_out);
}